// Round 2
// baseline (42.401 us; speedup 1.0000x reference)
//
#include <hip/hip_runtime.h>

// Problem: B=16, T=1024, S=1024, D=1024 (TARGET_SIZE=SOURCE_SIZE=1024)
//
// Key algebra: scores[b,t,s] = st[b,t] + gs[b,s]; softmax over s is
// shift-invariant, so the st term cancels EXACTLY:
//   attn[b,t,s] = softmax_s(gs[b,:])[s] = p[b,s]   (independent of t)
//   out[b,t,s]  = p[b,s]*keep[b,t,s] / (sum_s p[b,s]*keep[b,t,s] + 1e-12)
// sentence_state (64 MB) is never read.

constexpr int Bb = 16;
constexpr int Tt = 1024;
constexpr int Ss = 1024;
constexpr int Dd = 1024;

// ---------------------------------------------------------------------------
// Probe: decide whether mask is a 1-byte-per-element (bool/uint8) or a
// 4-byte-per-element (int32/float32) array. Samples first 1 KB (=256 elements
// in 4-byte form, 1024 in byte form; bernoulli(0.5) makes this statistically
// certain). Writes mode flag to ws_flag[0]: 0 = byte mask, 1 = word mask.
// ---------------------------------------------------------------------------
__global__ void mask_probe_kernel(const unsigned char* __restrict__ m,
                                  int* __restrict__ ws_flag) {
  __shared__ int nz[4];
  const int t = threadIdx.x;
  if (t < 4) nz[t] = 0;
  __syncthreads();
  uchar4 v = reinterpret_cast<const uchar4*>(m)[t];  // bytes 4t..4t+3
  if (v.x) atomicOr(&nz[0], 1);
  if (v.y) atomicOr(&nz[1], 1);
  if (v.z) atomicOr(&nz[2], 1);
  if (v.w) atomicOr(&nz[3], 1);
  __syncthreads();
  if (t == 0) {
    int spread = (nz[0] != 0) + (nz[1] != 0) + (nz[2] != 0) + (nz[3] != 0);
    // byte mask: ~50% of bytes nonzero in every residue class -> spread 4.
    // int32 0/1: only residue 0 nonzero (LE) -> spread 1.
    // float32 1.0f: bytes {0,0,0x80,0x3F} -> residues 2,3 -> spread 2.
    ws_flag[0] = (spread >= 3) ? 0 : 1;
  }
}

// ---------------------------------------------------------------------------
// gs[b,s] = dot(graph_state[b,s,:], w[1024:2048]); one wave per (b,s) row.
// ---------------------------------------------------------------------------
__global__ __launch_bounds__(256) void gs_dot_kernel(
    const float* __restrict__ graph, const float* __restrict__ w_full,
    float* __restrict__ gs) {
  const int lane = threadIdx.x & 63;
  const int wv   = threadIdx.x >> 6;
  const long row = (long)blockIdx.x * 4 + wv;  // < B*S = 16384
  const float4* r  = reinterpret_cast<const float4*>(graph) + row * (Dd / 4);
  const float4* ws = reinterpret_cast<const float4*>(w_full + 1024);
  float acc = 0.f;
#pragma unroll
  for (int k = 0; k < 4; ++k) {
    float4 a = r[lane + 64 * k];
    float4 b = ws[lane + 64 * k];
    acc = fmaf(a.x, b.x, acc);
    acc = fmaf(a.y, b.y, acc);
    acc = fmaf(a.z, b.z, acc);
    acc = fmaf(a.w, b.w, acc);
  }
#pragma unroll
  for (int off = 32; off; off >>= 1) acc += __shfl_xor(acc, off, 64);
  if (lane == 0) gs[row] = acc;
}

// ---------------------------------------------------------------------------
// Main kernel: block = 256 threads = 4 waves; grid = (T/4, B).
// Phase 1: block recomputes softmax(gs[b,:]) into LDS (4 KB).
// Phase 2: each wave owns one t-row: masked sum + renormalized float4 write.
// ---------------------------------------------------------------------------
__global__ __launch_bounds__(256) void PointerGenerator_9259949490200_kernel(
    const float* __restrict__ gs, const unsigned char* __restrict__ mask,
    const int* __restrict__ ws_flag, float* __restrict__ out) {
  __shared__ float p_sh[Ss];
  __shared__ float redbuf[8];
  const int tid  = threadIdx.x;
  const int lane = tid & 63;
  const int wv   = tid >> 6;
  const int b    = blockIdx.y;

  // ---- softmax over gs[b, :] (1024 values, 4 per thread) ----
  float4 g = reinterpret_cast<const float4*>(gs + (long)b * Ss)[tid];
  float m = fmaxf(fmaxf(g.x, g.y), fmaxf(g.z, g.w));
#pragma unroll
  for (int off = 32; off; off >>= 1) m = fmaxf(m, __shfl_xor(m, off, 64));
  if (lane == 0) redbuf[wv] = m;
  __syncthreads();
  m = fmaxf(fmaxf(redbuf[0], redbuf[1]), fmaxf(redbuf[2], redbuf[3]));
  float4 e = make_float4(__expf(g.x - m), __expf(g.y - m),
                         __expf(g.z - m), __expf(g.w - m));
  float zs = e.x + e.y + e.z + e.w;
#pragma unroll
  for (int off = 32; off; off >>= 1) zs += __shfl_xor(zs, off, 64);
  if (lane == 0) redbuf[4 + wv] = zs;
  __syncthreads();
  const float Z    = redbuf[4] + redbuf[5] + redbuf[6] + redbuf[7];
  const float invZ = 1.0f / Z;
  reinterpret_cast<float4*>(p_sh)[tid] =
      make_float4(e.x * invZ, e.y * invZ, e.z * invZ, e.w * invZ);
  __syncthreads();

  // ---- each wave: one t-row ----
  const long t    = (long)blockIdx.x * 4 + wv;
  const long row  = (long)b * Tt + t;
  const int  mode = ws_flag[0];  // 0 = byte mask, 1 = word mask (uniform)

  uchar4 mk[4];  // nonzero component => masked out
  if (mode == 0) {
    const uchar4* mrow = reinterpret_cast<const uchar4*>(mask + row * Ss);
#pragma unroll
    for (int k = 0; k < 4; ++k) mk[k] = mrow[lane + 64 * k];
  } else {
    const int4* mrow =
        reinterpret_cast<const int4*>(reinterpret_cast<const int*>(mask) + row * Ss);
#pragma unroll
    for (int k = 0; k < 4; ++k) {
      int4 w = mrow[lane + 64 * k];
      mk[k] = make_uchar4((unsigned char)(w.x != 0), (unsigned char)(w.y != 0),
                          (unsigned char)(w.z != 0), (unsigned char)(w.w != 0));
    }
  }

  float4 p[4];
  float sum = 0.f;
#pragma unroll
  for (int k = 0; k < 4; ++k) {
    const int idx = lane + 64 * k;
    p[k] = reinterpret_cast<const float4*>(p_sh)[idx];
    sum += (mk[k].x ? 0.f : p[k].x) + (mk[k].y ? 0.f : p[k].y) +
           (mk[k].z ? 0.f : p[k].z) + (mk[k].w ? 0.f : p[k].w);
  }
#pragma unroll
  for (int off = 32; off; off >>= 1) sum += __shfl_xor(sum, off, 64);
  const float invD = 1.0f / (sum + 1e-12f);
  float4* orow = reinterpret_cast<float4*>(out + row * Ss);
#pragma unroll
  for (int k = 0; k < 4; ++k) {
    const int idx = lane + 64 * k;
    float4 v;
    v.x = mk[k].x ? 0.f : p[k].x * invD;
    v.y = mk[k].y ? 0.f : p[k].y * invD;
    v.z = mk[k].z ? 0.f : p[k].z * invD;
    v.w = mk[k].w ? 0.f : p[k].w * invD;
    orow[idx] = v;
  }
}

extern "C" void kernel_launch(void* const* d_in, const int* in_sizes, int n_in,
                              void* d_out, int out_size, void* d_ws, size_t ws_size,
                              hipStream_t stream) {
  // inputs (setup_inputs order): [0] sentence_state (UNUSED — cancels in
  // softmax), [1] graph_state, [2] mask, [3] w (2048 floats)
  const float* graph        = (const float*)d_in[1];
  const unsigned char* mask = (const unsigned char*)d_in[2];
  const float* w            = (const float*)d_in[3];
  float* out = (float*)d_out;

  int*   ws_flag = (int*)d_ws;                          // [0]: mask mode
  float* gs      = (float*)((char*)d_ws + 256);         // B*S floats = 64 KB

  mask_probe_kernel<<<1, 256, 0, stream>>>(mask, ws_flag);
  gs_dot_kernel<<<(Bb * Ss) / 4, 256, 0, stream>>>(graph, w, gs);
  PointerGenerator_9259949490200_kernel<<<dim3(Tt / 4, Bb), 256, 0, stream>>>(
      gs, mask, ws_flag, out);
}

// Round 4
// 38.441 us; speedup vs baseline: 1.1030x; 1.1030x over previous
//
#include <hip/hip_runtime.h>

// Problem: B=16, T=1024, S=1024, D=1024 (TARGET_SIZE=SOURCE_SIZE=1024)
//
// Key algebra: scores[b,t,s] = st[b,t] + gs[b,s]; softmax over s is
// shift-invariant, so the st term cancels EXACTLY:
//   attn[b,t,s] = softmax_s(gs[b,:])[s] = p[b,s]   (independent of t)
//   out[b,t,s]  = p[b,s]*keep[b,t,s] / (sum_s p[b,s]*keep[b,t,s] + 1e-12)
// sentence_state (64 MB) is never read.
//
// HBM floor: 64 MB (graph) + 16 MB (mask bytes) + 64 MB (out) ~= 144 MB
// ~= 22 us at 6.5 TB/s.

constexpr int Bb = 16;
constexpr int Tt = 1024;
constexpr int Ss = 1024;
constexpr int Dd = 1024;

typedef float f32x4 __attribute__((ext_vector_type(4)));  // for nontemporal store

// ---------------------------------------------------------------------------
// K1: gs[b,s] = dot(graph_state[b,s,:], w[1024:2048]); one wave per (b,s) row.
// Pure 64 MB coalesced read -> ~10 us.
// ---------------------------------------------------------------------------
__global__ __launch_bounds__(256) void gs_dot_kernel(
    const float* __restrict__ graph, const float* __restrict__ w_full,
    float* __restrict__ gs) {
  const int lane = threadIdx.x & 63;
  const int wv   = threadIdx.x >> 6;
  const long row = (long)blockIdx.x * 4 + wv;  // < B*S = 16384
  const float4* r  = reinterpret_cast<const float4*>(graph) + row * (Dd / 4);
  const float4* ws = reinterpret_cast<const float4*>(w_full + 1024);
  float acc = 0.f;
#pragma unroll
  for (int k = 0; k < 4; ++k) {
    float4 a = r[lane + 64 * k];
    float4 b = ws[lane + 64 * k];
    acc = fmaf(a.x, b.x, acc);
    acc = fmaf(a.y, b.y, acc);
    acc = fmaf(a.z, b.z, acc);
    acc = fmaf(a.w, b.w, acc);
  }
#pragma unroll
  for (int off = 32; off; off >>= 1) acc += __shfl_xor(acc, off, 64);
  if (lane == 0) gs[row] = acc;
}

// ---------------------------------------------------------------------------
// K2: p[b,:] = softmax(gs[b,:]). 16 blocks (one per b), 256 threads.
// Block 0 also probes the mask element size (1B bool vs 4B int/float):
// samples first 1024 bytes; bernoulli(0.5) bools are nonzero in all 4 byte
// residues; int32 0/1 only residue 0; float32 1.0f residues 2,3.
// ws_flag[0]: 0 = byte mask, 1 = word mask.
// ---------------------------------------------------------------------------
__global__ __launch_bounds__(256) void softmax_probe_kernel(
    const float* __restrict__ gs, const unsigned char* __restrict__ mask,
    int* __restrict__ ws_flag, float* __restrict__ p) {
  __shared__ float redbuf[8];
  __shared__ int nz[4];
  const int tid  = threadIdx.x;
  const int lane = tid & 63;
  const int wv   = tid >> 6;
  const int b    = blockIdx.x;

  if (b == 0) {
    if (tid < 4) nz[tid] = 0;
    __syncthreads();
    uchar4 v = reinterpret_cast<const uchar4*>(mask)[tid];
    if (v.x) atomicOr(&nz[0], 1);
    if (v.y) atomicOr(&nz[1], 1);
    if (v.z) atomicOr(&nz[2], 1);
    if (v.w) atomicOr(&nz[3], 1);
    __syncthreads();
    if (tid == 0) {
      int spread = (nz[0] != 0) + (nz[1] != 0) + (nz[2] != 0) + (nz[3] != 0);
      ws_flag[0] = (spread >= 3) ? 0 : 1;
    }
  }

  float4 g = reinterpret_cast<const float4*>(gs + (long)b * Ss)[tid];
  float m = fmaxf(fmaxf(g.x, g.y), fmaxf(g.z, g.w));
#pragma unroll
  for (int off = 32; off; off >>= 1) m = fmaxf(m, __shfl_xor(m, off, 64));
  if (lane == 0) redbuf[wv] = m;
  __syncthreads();
  m = fmaxf(fmaxf(redbuf[0], redbuf[1]), fmaxf(redbuf[2], redbuf[3]));
  float4 e = make_float4(__expf(g.x - m), __expf(g.y - m),
                         __expf(g.z - m), __expf(g.w - m));
  float zs = e.x + e.y + e.z + e.w;
#pragma unroll
  for (int off = 32; off; off >>= 1) zs += __shfl_xor(zs, off, 64);
  if (lane == 0) redbuf[4 + wv] = zs;
  __syncthreads();
  const float Z    = redbuf[4] + redbuf[5] + redbuf[6] + redbuf[7];
  const float invZ = 1.0f / Z;
  reinterpret_cast<float4*>(p + (long)b * Ss)[tid] =
      make_float4(e.x * invZ, e.y * invZ, e.z * invZ, e.w * invZ);
}

// ---------------------------------------------------------------------------
// K3: stream kernel. One wave owns ROWS=4 consecutive t-rows; p[b,:] is
// register-resident (4 x float4 per lane), amortized across rows. SoA
// processing: 4 independent reduce chains pipeline the shfl latency.
// No LDS. Nontemporal stores for out (write-once, keep L2 for mask).
// Grid: (T / (ROWS*4waves) = 64, B).
// ---------------------------------------------------------------------------
__global__ __launch_bounds__(256) void PointerGenerator_9259949490200_kernel(
    const float* __restrict__ p, const unsigned char* __restrict__ mask,
    const int* __restrict__ ws_flag, float* __restrict__ out) {
  constexpr int ROWS = 4;
  const int lane = threadIdx.x & 63;
  const int wv   = threadIdx.x >> 6;
  const int b    = blockIdx.y;

  // p[b,:] -> registers (L2-hot: 64 KB total across all b)
  const float4* p4 = reinterpret_cast<const float4*>(p + (long)b * Ss);
  float4 pr[4];
#pragma unroll
  for (int k = 0; k < 4; ++k) pr[k] = p4[lane + 64 * k];

  const int  mode = ws_flag[0];  // uniform branch
  const long t0   = (long)blockIdx.x * (4 * ROWS) + (long)wv * ROWS;
  const long row0 = (long)b * Tt + t0;

  uchar4 mk[ROWS][4];
  if (mode == 0) {
    const uchar4* m4 = reinterpret_cast<const uchar4*>(mask + row0 * Ss);
#pragma unroll
    for (int r = 0; r < ROWS; ++r)
#pragma unroll
      for (int k = 0; k < 4; ++k) mk[r][k] = m4[r * 256 + lane + 64 * k];
  } else {
    const int4* m4 = reinterpret_cast<const int4*>(
        reinterpret_cast<const int*>(mask) + row0 * Ss);
#pragma unroll
    for (int r = 0; r < ROWS; ++r)
#pragma unroll
      for (int k = 0; k < 4; ++k) {
        int4 w = m4[r * 256 + lane + 64 * k];
        mk[r][k] = make_uchar4((unsigned char)(w.x != 0), (unsigned char)(w.y != 0),
                               (unsigned char)(w.z != 0), (unsigned char)(w.w != 0));
      }
  }

  float sum[ROWS];
#pragma unroll
  for (int r = 0; r < ROWS; ++r) {
    float s = 0.f;
#pragma unroll
    for (int k = 0; k < 4; ++k) {
      s += (mk[r][k].x ? 0.f : pr[k].x) + (mk[r][k].y ? 0.f : pr[k].y) +
           (mk[r][k].z ? 0.f : pr[k].z) + (mk[r][k].w ? 0.f : pr[k].w);
    }
    sum[r] = s;
  }
  // 4 independent butterfly chains (pipelined)
#pragma unroll
  for (int off = 32; off; off >>= 1)
#pragma unroll
    for (int r = 0; r < ROWS; ++r) sum[r] += __shfl_xor(sum[r], off, 64);

#pragma unroll
  for (int r = 0; r < ROWS; ++r) {
    const float invD = 1.0f / (sum[r] + 1e-12f);
    f32x4* orow = reinterpret_cast<f32x4*>(out + (row0 + r) * Ss);
#pragma unroll
    for (int k = 0; k < 4; ++k) {
      f32x4 v;
      v.x = mk[r][k].x ? 0.f : pr[k].x * invD;
      v.y = mk[r][k].y ? 0.f : pr[k].y * invD;
      v.z = mk[r][k].z ? 0.f : pr[k].z * invD;
      v.w = mk[r][k].w ? 0.f : pr[k].w * invD;
      __builtin_nontemporal_store(v, &orow[lane + 64 * k]);
    }
  }
}

extern "C" void kernel_launch(void* const* d_in, const int* in_sizes, int n_in,
                              void* d_out, int out_size, void* d_ws, size_t ws_size,
                              hipStream_t stream) {
  // inputs (setup_inputs order): [0] sentence_state (UNUSED — cancels in
  // softmax), [1] graph_state, [2] mask, [3] w (2048 floats)
  const float* graph        = (const float*)d_in[1];
  const unsigned char* mask = (const unsigned char*)d_in[2];
  const float* w            = (const float*)d_in[3];
  float* out = (float*)d_out;

  int*   ws_flag = (int*)d_ws;                    // [0]: mask mode
  float* gs      = (float*)((char*)d_ws + 256);   // B*S floats = 64 KB
  float* p       = gs + Bb * Ss;                  // B*S floats = 64 KB

  gs_dot_kernel<<<(Bb * Ss) / 4, 256, 0, stream>>>(graph, w, gs);
  softmax_probe_kernel<<<Bb, 256, 0, stream>>>(gs, mask, ws_flag, p);
  PointerGenerator_9259949490200_kernel<<<dim3(Tt / (4 * 4), Bb), 256, 0, stream>>>(
      p, mask, ws_flag, out);
}